// Round 11
// baseline (3423.997 us; speedup 1.0000x reference)
//
#include <hip/hip_runtime.h>
#include <math.h>

// ---- problem constants ----
#define NT   16384
#define HD   4096
#define NE   64
#define TOPK 8

// ---- d_out layout: FLOAT32 elements (proven rounds 5/7/8/9) ----
#define L_OFF 0
#define W_OFF (NT * NE)                  // 1048576
#define I_OFF (W_OFF + NT * TOPK)        // 1179648
#define M_OFF (I_OFF + NT * TOPK)        // 1310720 ; mask = NE*TOPK*NT floats

#define BK 64                            // K-chunk
#define XP 65                            // x LDS stride (padded)

typedef __attribute__((ext_vector_type(4))) float f4;

// ---- kernel A: zero the fp32 mask region ----
__global__ __launch_bounds__(256) void kz_mask(f4* __restrict__ p, int n4) {
  f4 z = {0.f, 0.f, 0.f, 0.f};
  for (int i = blockIdx.x * 256 + threadIdx.x; i < n4; i += gridDim.x * 256) p[i] = z;
}

// ---- kernel B: fp32 VALU GEMM; lane=token; w via LDS BROADCAST reads ----
// block 512 thr (8 waves) = tile 64 tokens x 64 experts; wave wv: experts wv*8..+7,
// lane = token. Per st-step/thread: 1 per-lane ds_read_b128 (x) + 8 broadcast
// ds_read_b128 (w, wave-uniform addr) + 32 fma. Both x and w double-buffered in
// LDS, 1 barrier/chunk; global loads for chunk c+2 issued during chunk c.
// Per-(t,e) accumulation BITWISE-IDENTICAL to rounds 5-9: 4 component chains
// (k mod 4), k ascending, final ((c0+c1)+c2)+c3 + bias.
__global__ __launch_bounds__(512, 2) void k_gemm(const float* __restrict__ x,
                                                 const float* __restrict__ w,
                                                 const float* __restrict__ bias,
                                                 float* __restrict__ out) {
  __shared__ float xs0[64 * XP], xs1[64 * XP];   // 2 x 16.6 KB
  __shared__ float ws0[64 * BK], ws1[64 * BK];   // 2 x 16.0 KB

  const int tid  = threadIdx.x;
  const int lane = tid & 63;             // token within tile
  const int wv   = tid >> 6;             // 0..7
  const int e0   = wv * 8;               // this wave's experts
  const int tok0 = blockIdx.x * 64;

  f4 acc[8];
#pragma unroll
  for (int s = 0; s < 8; ++s) acc[s] = (f4){0.f, 0.f, 0.f, 0.f};

  // staging ownership: 1024 f4-units per tile (x and w each); thread stages
  // units tid and tid+512 of each: row r0=tid>>4 and r0+32, 16B-unit su.
  const int r0 = tid >> 4;               // 0..31
  const int su = tid & 15;
  const float* xb0 = x + (size_t)(tok0 + r0) * HD + su * 4;
  const float* xb1 = x + (size_t)(tok0 + r0 + 32) * HD + su * 4;
  const float* wb0 = w + (size_t)r0 * HD + su * 4;
  const float* wb1 = w + (size_t)(r0 + 32) * HD + su * 4;

#define LOADSET(X0, X1, W0, W1, c)                 \
  do { const int kc_ = (c) * BK;                   \
    X0 = *(const f4*)(xb0 + kc_);                  \
    X1 = *(const f4*)(xb1 + kc_);                  \
    W0 = *(const f4*)(wb0 + kc_);                  \
    W1 = *(const f4*)(wb1 + kc_);                  \
  } while (0)

#define WRITESET(XS, WS, X0, X1, W0, W1)           \
  do {                                             \
    *(f4*)(&XS[r0 * XP + su * 4])        = X0;     \
    *(f4*)(&XS[(r0 + 32) * XP + su * 4]) = X1;     \
    *(f4*)(&WS[r0 * BK + su * 4])        = W0;     \
    *(f4*)(&WS[(r0 + 32) * BK + su * 4]) = W1;     \
  } while (0)

#define COMPUTE(XS, WS)                                              \
  do {                                                               \
    _Pragma("unroll")                                                \
    for (int st = 0; st < 16; ++st) {                                \
      const int k0 = st * 4;                                         \
      f4 xv = *(const f4*)(&XS[lane * XP + k0]);                     \
      _Pragma("unroll")                                              \
      for (int s = 0; s < 8; ++s) {                                  \
        f4 wf = *(const f4*)(&WS[(e0 + s) * BK + k0]);  /* bcast */  \
        acc[s][0] = fmaf(xv[0], wf[0], acc[s][0]);                   \
        acc[s][1] = fmaf(xv[1], wf[1], acc[s][1]);                   \
        acc[s][2] = fmaf(xv[2], wf[2], acc[s][2]);                   \
        acc[s][3] = fmaf(xv[3], wf[3], acc[s][3]);                   \
      }                                                              \
    }                                                                \
  } while (0)

  f4 xA0, xA1, wA0, wA1;                 // ping
  f4 xB0, xB1, wB0, wB1;                 // pong

  // prologue: chunk0 -> regsA -> buf0; chunk1 -> regsB (in flight)
  LOADSET(xA0, xA1, wA0, wA1, 0);
  LOADSET(xB0, xB1, wB0, wB1, 1);
  WRITESET(xs0, ws0, xA0, xA1, wA0, wA1);
  __syncthreads();

  for (int cc = 0; cc < HD / BK; cc += 2) {
    // even chunk cc: buf0 compute; stage cc+1 (regsB) -> buf1; load cc+2 -> regsA
    if (cc + 1 < HD / BK) WRITESET(xs1, ws1, xB0, xB1, wB0, wB1);
    if (cc + 2 < HD / BK) LOADSET(xA0, xA1, wA0, wA1, cc + 2);
    COMPUTE(xs0, ws0);
    __syncthreads();
    // odd chunk cc+1: buf1 compute; stage cc+2 (regsA) -> buf0; load cc+3 -> regsB
    if (cc + 1 < HD / BK) {
      if (cc + 2 < HD / BK) WRITESET(xs0, ws0, xA0, xA1, wA0, wA1);
      if (cc + 3 < HD / BK) LOADSET(xB0, xB1, wB0, wB1, cc + 3);
      COMPUTE(xs1, ws1);
      __syncthreads();
    }
  }

  // epilogue: same final-sum order as rounds 5-9; experts e0..e0+7 consecutive
  float res[8];
#pragma unroll
  for (int s = 0; s < 8; ++s)
    res[s] = acc[s][0] + acc[s][1] + acc[s][2] + acc[s][3] + bias[e0 + s];
  float* dst = out + L_OFF + (size_t)(tok0 + lane) * NE + e0;
  *(f4*)(dst)     = (f4){res[0], res[1], res[2], res[3]};
  *(f4*)(dst + 4) = (f4){res[4], res[5], res[6], res[7]};
#undef LOADSET
#undef WRITESET
#undef COMPUTE
}

// ---- kernel C: top-8 from stored fp32 logits (rounds 5-9 verbatim selection) ----
__global__ __launch_bounds__(256) void k_topk(float* __restrict__ out) {
  const int lane = threadIdx.x & 63;            // lane == expert
  const int wv   = threadIdx.x >> 6;
  const int t    = blockIdx.x * 4 + wv;

  float v = out[L_OFF + (size_t)t * NE + lane];

  // rank = #{e : v_e > v or (v_e == v and e < lane)}  (stable, lax.top_k order)
  int rank = 0;
  for (int e = 0; e < NE; ++e) {
    float ve = __shfl(v, e);
    rank += (ve > v) || (ve == v && e < lane);
  }

  // weights = softmax over the selected 8 (global Z cancels in renormalization)
  float m0 = v;
#pragma unroll
  for (int o = 32; o; o >>= 1) m0 = fmaxf(m0, __shfl_xor(m0, o));
  float ev = (rank < TOPK) ? expf(v - m0) : 0.f;
  float s = ev;
#pragma unroll
  for (int o = 32; o; o >>= 1) s += __shfl_xor(s, o);

  if (rank < TOPK) {
    out[W_OFF + (size_t)t * TOPK + rank] = ev / s;
    out[I_OFF + (size_t)t * TOPK + rank] = (float)lane;                  // exact (<=63)
    out[M_OFF + ((size_t)lane * TOPK + rank) * NT + t] = 1.0f;           // mask one-hot
  }
}

extern "C" void kernel_launch(void* const* d_in, const int* in_sizes, int n_in,
                              void* d_out, int out_size, void* d_ws, size_t ws_size,
                              hipStream_t stream) {
  const float* x  = (const float*)d_in[0];
  const float* gw = (const float*)d_in[1];
  const float* gb = (const float*)d_in[2];
  float* out = (float*)d_out;

  kz_mask<<<2048, 256, 0, stream>>>((f4*)(out + M_OFF), (NE * TOPK * NT) / 4);
  k_gemm <<<NT / 64, 512, 0, stream>>>(x, gw, gb, out);
  k_topk <<<NT / 4, 256, 0, stream>>>(out);
}

// Round 12
// 200.049 us; speedup vs baseline: 17.1158x; 17.1158x over previous
//
#include <hip/hip_runtime.h>
#include <math.h>

// ---- problem constants ----
#define NT   16384
#define HD   4096
#define NE   64
#define TOPK 8

// ---- d_out layout: FLOAT32 elements (proven rounds 5/7/8/9) ----
#define L_OFF 0
#define W_OFF (NT * NE)                  // 1048576
#define I_OFF (W_OFF + NT * TOPK)        // 1179648
#define M_OFF (I_OFF + NT * TOPK)        // 1310720 ; mask = NE*TOPK*NT floats

#define BK 64                            // K-chunk
#define XP 68                            // x LDS stride (floats): rows 16B-aligned, banks spread
#define WP 68                            // w LDS stride

typedef __attribute__((ext_vector_type(4))) float f4;

// ---- kernel A: zero the fp32 mask region ----
__global__ __launch_bounds__(256) void kz_mask(f4* __restrict__ p, int n4) {
  f4 z = {0.f, 0.f, 0.f, 0.f};
  for (int i = blockIdx.x * 256 + threadIdx.x; i < n4; i += gridDim.x * 256) p[i] = z;
}

// ---- kernel B: fp32 VALU GEMM; lane=EXPERT, x via LDS broadcasts ----
// block 256 thr (4 waves) = tile 32 tokens x 64 experts; wave wv: tokens wv*8..+7,
// lane = expert. Per st-step/thread: 1 per-lane ds_read_b128 (w[lane]) +
// 8 broadcast ds_read_b128 (x, wave-uniform addr) + 32 fma.
// x,w double-buffered in LDS; 1 barrier/chunk; loads for c+2 issued during c.
// Per-(t,e) accumulation BITWISE-IDENTICAL to rounds 5-9: 4 component chains
// (k mod 4), k ascending, final ((c0+c1)+c2)+c3 + bias.
__global__ __launch_bounds__(256, 2) void k_gemm(const float* __restrict__ x,
                                                 const float* __restrict__ w,
                                                 const float* __restrict__ bias,
                                                 float* __restrict__ out) {
  __shared__ float xs0[32 * XP], xs1[32 * XP];   // 8.7 KB each
  __shared__ float ws0[64 * WP], ws1[64 * WP];   // 17.4 KB each  (total 52.2 KB)

  const int tid  = threadIdx.x;
  const int lane = tid & 63;             // expert
  const int wv   = tid >> 6;             // 0..3 -> tokens wv*8..wv*8+7
  const int tok0 = blockIdx.x * 32;

  f4 acc[8];
#pragma unroll
  for (int j = 0; j < 8; ++j) acc[j] = (f4){0.f, 0.f, 0.f, 0.f};

  // staging ownership: x 512 units (rows xr, xr+16), w 1024 units (rows xr+16i)
  const int xr = tid >> 4;               // 0..15
  const int su = tid & 15;
  const float* xg0 = x + (size_t)(tok0 + xr) * HD + su * 4;
  const float* xg1 = x + (size_t)(tok0 + xr + 16) * HD + su * 4;
  const float* wg0 = w + (size_t)(xr +  0) * HD + su * 4;
  const float* wg1 = w + (size_t)(xr + 16) * HD + su * 4;
  const float* wg2 = w + (size_t)(xr + 32) * HD + su * 4;
  const float* wg3 = w + (size_t)(xr + 48) * HD + su * 4;

  // prologue: chunk0 -> regs -> buf0; chunk1 -> regs (in flight)
  f4 rx0 = *(const f4*)(xg0), rx1 = *(const f4*)(xg1);
  f4 rw0 = *(const f4*)(wg0), rw1 = *(const f4*)(wg1);
  f4 rw2 = *(const f4*)(wg2), rw3 = *(const f4*)(wg3);

  float* xc = xs0; float* xn = xs1;
  float* wc = ws0; float* wn = ws1;

  *(f4*)(xc + xr * XP + su * 4)        = rx0;
  *(f4*)(xc + (xr + 16) * XP + su * 4) = rx1;
  *(f4*)(wc + (xr +  0) * WP + su * 4) = rw0;
  *(f4*)(wc + (xr + 16) * WP + su * 4) = rw1;
  *(f4*)(wc + (xr + 32) * WP + su * 4) = rw2;
  *(f4*)(wc + (xr + 48) * WP + su * 4) = rw3;

  rx0 = *(const f4*)(xg0 + BK); rx1 = *(const f4*)(xg1 + BK);
  rw0 = *(const f4*)(wg0 + BK); rw1 = *(const f4*)(wg1 + BK);
  rw2 = *(const f4*)(wg2 + BK); rw3 = *(const f4*)(wg3 + BK);
  __syncthreads();

  for (int c = 0; c < HD / BK; ++c) {
    // stage chunk c+1 (regs landed) into next buffers
    if (c + 1 < HD / BK) {
      *(f4*)(xn + xr * XP + su * 4)        = rx0;
      *(f4*)(xn + (xr + 16) * XP + su * 4) = rx1;
      *(f4*)(wn + (xr +  0) * WP + su * 4) = rw0;
      *(f4*)(wn + (xr + 16) * WP + su * 4) = rw1;
      *(f4*)(wn + (xr + 32) * WP + su * 4) = rw2;
      *(f4*)(wn + (xr + 48) * WP + su * 4) = rw3;
    }
    // issue chunk c+2 global loads; they land under this chunk's compute
    if (c + 2 < HD / BK) {
      const int kc = (c + 2) * BK;
      rx0 = *(const f4*)(xg0 + kc); rx1 = *(const f4*)(xg1 + kc);
      rw0 = *(const f4*)(wg0 + kc); rw1 = *(const f4*)(wg1 + kc);
      rw2 = *(const f4*)(wg2 + kc); rw3 = *(const f4*)(wg3 + kc);
    }

    // compute chunk c: per st: 1 per-lane b128 (w) + 8 bcast b128 (x) + 32 fma
#pragma unroll
    for (int st = 0; st < 16; ++st) {
      const int k0 = st * 4;
      f4 wf = *(const f4*)(wc + lane * WP + k0);      // per-lane: own expert row
#pragma unroll
      for (int j = 0; j < 8; ++j) {
        f4 xv = *(const f4*)(xc + (wv * 8 + j) * XP + k0);   // wave-uniform bcast
        acc[j][0] = fmaf(xv[0], wf[0], acc[j][0]);
        acc[j][1] = fmaf(xv[1], wf[1], acc[j][1]);
        acc[j][2] = fmaf(xv[2], wf[2], acc[j][2]);
        acc[j][3] = fmaf(xv[3], wf[3], acc[j][3]);
      }
    }
    __syncthreads();
    float* t;
    t = xc; xc = xn; xn = t;
    t = wc; wc = wn; wn = t;
  }

  // epilogue: same final-sum order as rounds 5-9
  const float b = bias[lane];
#pragma unroll
  for (int j = 0; j < 8; ++j) {
    float v = acc[j][0] + acc[j][1] + acc[j][2] + acc[j][3] + b;
    out[L_OFF + (size_t)(tok0 + wv * 8 + j) * NE + lane] = v;   // coalesced per token
  }
}

// ---- kernel C: top-8 from stored fp32 logits (rounds 5-9 verbatim selection) ----
__global__ __launch_bounds__(256) void k_topk(float* __restrict__ out) {
  const int lane = threadIdx.x & 63;            // lane == expert
  const int wv   = threadIdx.x >> 6;
  const int t    = blockIdx.x * 4 + wv;

  float v = out[L_OFF + (size_t)t * NE + lane];

  // rank = #{e : v_e > v or (v_e == v and e < lane)}  (stable, lax.top_k order)
  int rank = 0;
  for (int e = 0; e < NE; ++e) {
    float ve = __shfl(v, e);
    rank += (ve > v) || (ve == v && e < lane);
  }

  // weights = softmax over the selected 8 (global Z cancels in renormalization)
  float m0 = v;
#pragma unroll
  for (int o = 32; o; o >>= 1) m0 = fmaxf(m0, __shfl_xor(m0, o));
  float ev = (rank < TOPK) ? expf(v - m0) : 0.f;
  float s = ev;
#pragma unroll
  for (int o = 32; o; o >>= 1) s += __shfl_xor(s, o);

  if (rank < TOPK) {
    out[W_OFF + (size_t)t * TOPK + rank] = ev / s;
    out[I_OFF + (size_t)t * TOPK + rank] = (float)lane;                  // exact (<=63)
    out[M_OFF + ((size_t)lane * TOPK + rank) * NT + t] = 1.0f;           // mask one-hot
  }
}

extern "C" void kernel_launch(void* const* d_in, const int* in_sizes, int n_in,
                              void* d_out, int out_size, void* d_ws, size_t ws_size,
                              hipStream_t stream) {
  const float* x  = (const float*)d_in[0];
  const float* gw = (const float*)d_in[1];
  const float* gb = (const float*)d_in[2];
  float* out = (float*)d_out;

  kz_mask<<<2048, 256, 0, stream>>>((f4*)(out + M_OFF), (NE * TOPK * NT) / 4);
  k_gemm <<<NT / 32, 256, 0, stream>>>(x, gw, gb, out);
  k_topk <<<NT / 4, 256, 0, stream>>>(out);
}